// Round 7
// baseline (387.037 us; speedup 1.0000x reference)
//
#include <hip/hip_runtime.h>

#define NFEAT 256
#define NHID 64
#define NHEAD 8
#define HID1 512   // NHEAD*NHID
#define NOUT 128

typedef unsigned short ushort_t;
typedef unsigned int uint_t;
typedef __attribute__((ext_vector_type(8))) short short8;
typedef __attribute__((ext_vector_type(4))) float floatx4;
typedef __attribute__((ext_vector_type(4))) ushort_t ushort4_t;

static __device__ __forceinline__ float bf2f(uint_t s) {
    return __uint_as_float(s << 16);
}
static __device__ __forceinline__ ushort_t f2bf(float f) {
    uint_t u = __float_as_uint(f);
    u += 0x7FFF + ((u >> 16) & 1);   // RNE; inputs finite
    return (ushort_t)(u >> 16);
}

// ---------------- fused prep: cast x, transpose W1/W2, degree histogram ----------------
__global__ void k_prep(const float* __restrict__ x, ushort_t* __restrict__ xb,
                       const float* __restrict__ W1, ushort_t* __restrict__ W1t,
                       const float* __restrict__ W2, ushort_t* __restrict__ W2t,
                       const int* __restrict__ dstA, int* __restrict__ deg,
                       int n, int E, int c0, int c1, int c2) {
    int blk = blockIdx.x;
    int t = threadIdx.x;
    if (blk < c0) {                       // cast x -> bf16, 4 elems/thread
        int i = blk * 256 + t;
        floatx4 f = ((const floatx4*)x)[i];
        ushort4_t o;
        #pragma unroll
        for (int j = 0; j < 4; ++j) o[j] = f2bf(f[j]);
        ((ushort4_t*)xb)[i] = o;
    } else if (blk < c1) {                // W1[K][N] -> W1t[N][K] bf16
        int i = (blk - c0) * 256 + t;
        int nn = i / NFEAT, kk = i % NFEAT;
        W1t[i] = f2bf(W1[(size_t)kk * HID1 + nn]);
    } else if (blk < c2) {                // W2[K][N] -> W2t[N][K] bf16
        int i = (blk - c1) * 256 + t;
        int nn = i / HID1, kk = i % HID1;
        W2t[i] = f2bf(W2[(size_t)kk * NOUT + nn]);
    } else {                              // degree histogram (self-loops appended)
        int i = (blk - c2) * 256 + t;
        if (i < E + n) {
            int d = (i < E) ? dstA[i] : (i - E);
            atomicAdd(&deg[d], 1);
        }
    }
}

// ---------------- single-block scan ----------------
__global__ __launch_bounds__(1024) void k_scan(const int* __restrict__ deg, int* __restrict__ indptr, int n) {
    __shared__ int part[1024];
    int t = threadIdx.x;
    int chunk = (n + 1023) >> 10;
    int b = t * chunk;
    int e = min(b + chunk, n);
    int s = 0;
    int i = b;
    for (; i + 3 < e; i += 4)
        s += (deg[i] + deg[i + 1]) + (deg[i + 2] + deg[i + 3]);
    for (; i < e; ++i) s += deg[i];
    part[t] = s;
    __syncthreads();
    for (int off = 1; off < 1024; off <<= 1) {
        int v = (t >= off) ? part[t - off] : 0;
        __syncthreads();
        part[t] += v;
        __syncthreads();
    }
    int run = (t == 0) ? 0 : part[t - 1];
    i = b;
    for (; i + 3 < e; i += 4) {
        int d0 = deg[i], d1 = deg[i + 1], d2 = deg[i + 2], d3 = deg[i + 3];
        indptr[i] = run; run += d0;
        indptr[i + 1] = run; run += d1;
        indptr[i + 2] = run; run += d2;
        indptr[i + 3] = run; run += d3;
    }
    for (; i < e; ++i) { indptr[i] = run; run += deg[i]; }
    if (t == 1023) indptr[n] = part[1023];
}

__global__ void k_fill(const int* __restrict__ srcA, const int* __restrict__ dstA, int E, int n,
                       const int* __restrict__ indptr, int* __restrict__ cnt,
                       int* __restrict__ csr_src) {
    int i = blockIdx.x * blockDim.x + threadIdx.x;
    if (i >= E + n) return;
    int s, d;
    if (i < E) { s = srcA[i]; d = dstA[i]; } else { s = i - E; d = s; }
    int pos = indptr[d] + atomicAdd(&cnt[d], 1);
    csr_src[pos] = s;
}

// ---------------- GEMM1: 128x256 tile + fused el1/er1 epilogue ----------------
// C[M,512] = A[M,256] @ Bt[512,256]^T (bf16). Wave covers 64 rows x 128 cols
// (= 2 heads), el/er reduce within-wave over l16 — no atomics.
__global__ __launch_bounds__(256) void k_gemm1(const ushort_t* __restrict__ A,
                                               const ushort_t* __restrict__ Bt,
                                               ushort_t* __restrict__ C,
                                               const float* __restrict__ al,
                                               const float* __restrict__ ar,
                                               float* __restrict__ el, float* __restrict__ er,
                                               int M) {
    const int N = HID1, K = NFEAT;
    __shared__ __align__(16) ushort_t As[128 * 32];   // 8 KB
    __shared__ __align__(16) ushort_t Bs[256 * 32];   // 16 KB
    const int t = threadIdx.x;
    const int w = t >> 6, lane = t & 63;
    const int l16 = lane & 15, quad = lane >> 4;
    const int m0 = blockIdx.y * 128, n0 = blockIdx.x * 256;
    const int r0 = (w >> 1) * 64;     // wave row base (local)
    const int c0 = (w & 1) * 128;     // wave col base (local) — 2 heads

    floatx4 acc[4][8] = {};

    const int skp = (t & 3) * 8;
    // staging pass j: rows [j*64, j*64+64), LDS base (j*256 + (t&~63))*8
    for (int k0 = 0; k0 < K; k0 += 32) {
        #pragma unroll
        for (int j = 0; j < 2; ++j) {       // A: 128 rows, 2 passes
            int r = (j * 256 + t) >> 2;
            int gr = m0 + r; if (gr >= M) gr = M - 1;
            const ushort_t* gp = A + (size_t)gr * K + k0 + skp;
            __builtin_amdgcn_global_load_lds((const __attribute__((address_space(1))) void*)gp,
                (__attribute__((address_space(3))) void*)(As + (j * 256 + (t & ~63)) * 8), 16, 0, 0);
        }
        #pragma unroll
        for (int j = 0; j < 4; ++j) {       // B: 256 rows, 4 passes (N=512 exact, no clamp)
            int r = (j * 256 + t) >> 2;
            const ushort_t* gp = Bt + (size_t)(n0 + r) * K + k0 + skp;
            __builtin_amdgcn_global_load_lds((const __attribute__((address_space(1))) void*)gp,
                (__attribute__((address_space(3))) void*)(Bs + (j * 256 + (t & ~63)) * 8), 16, 0, 0);
        }
        __syncthreads();

        short8 af[4], bf[8];
        #pragma unroll
        for (int i = 0; i < 4; ++i)
            af[i] = *(const short8*)(As + (r0 + i * 16 + l16) * 32 + quad * 8);
        #pragma unroll
        for (int j = 0; j < 8; ++j)
            bf[j] = *(const short8*)(Bs + (c0 + j * 16 + l16) * 32 + quad * 8);
        #pragma unroll
        for (int i = 0; i < 4; ++i)
            #pragma unroll
            for (int j = 0; j < 8; ++j)
                acc[i][j] = __builtin_amdgcn_mfma_f32_16x16x32_bf16(af[i], bf[j], acc[i][j], 0, 0, 0);
        __syncthreads();
    }

    // C store
    #pragma unroll
    for (int i = 0; i < 4; ++i) {
        #pragma unroll
        for (int r = 0; r < 4; ++r) {
            int row = m0 + r0 + i * 16 + quad * 4 + r;
            if (row < M) {
                #pragma unroll
                for (int j = 0; j < 8; ++j)
                    C[(size_t)row * N + n0 + c0 + j * 16 + l16] = f2bf(acc[i][j][r]);
            }
        }
    }

    // fused el/er: wave covers heads head0, head0+1
    float alv[8], arv[8];
    #pragma unroll
    for (int j = 0; j < 8; ++j) {
        int col = n0 + c0 + j * 16 + l16;
        alv[j] = al[col];
        arv[j] = ar[col];
    }
    int head0 = (n0 + c0) >> 6;
    #pragma unroll
    for (int i = 0; i < 4; ++i) {
        #pragma unroll
        for (int r = 0; r < 4; ++r) {
            float pa = acc[i][0][r] * alv[0] + acc[i][1][r] * alv[1]
                     + acc[i][2][r] * alv[2] + acc[i][3][r] * alv[3];
            float qa = acc[i][0][r] * arv[0] + acc[i][1][r] * arv[1]
                     + acc[i][2][r] * arv[2] + acc[i][3][r] * arv[3];
            float pb = acc[i][4][r] * alv[4] + acc[i][5][r] * alv[5]
                     + acc[i][6][r] * alv[6] + acc[i][7][r] * alv[7];
            float qb = acc[i][4][r] * arv[4] + acc[i][5][r] * arv[5]
                     + acc[i][6][r] * arv[6] + acc[i][7][r] * arv[7];
            #pragma unroll
            for (int o = 8; o > 0; o >>= 1) {
                pa += __shfl_down(pa, o);
                qa += __shfl_down(qa, o);
                pb += __shfl_down(pb, o);
                qb += __shfl_down(qb, o);
            }
            if (l16 == 0) {
                int row = m0 + r0 + i * 16 + quad * 4 + r;
                if (row < M) {
                    el[row * NHEAD + head0] = pa;
                    er[row * NHEAD + head0] = qa;
                    el[row * NHEAD + head0 + 1] = pb;
                    er[row * NHEAD + head0 + 1] = qb;
                }
            }
        }
    }
}

// ---------------- GEMM2: 64x128 tile + fused el2/er2 epilogue ----------------
__global__ __launch_bounds__(256) void k_gemm2(const ushort_t* __restrict__ A,
                                               const ushort_t* __restrict__ Bt,
                                               ushort_t* __restrict__ C,
                                               const float* __restrict__ al,
                                               const float* __restrict__ ar,
                                               float* __restrict__ el, float* __restrict__ er,
                                               int M) {
    const int N = NOUT, K = HID1;
    __shared__ __align__(16) ushort_t As[64 * 32];
    __shared__ __align__(16) ushort_t Bs[128 * 32];
    __shared__ float elp[64][2], erp[64][2];
    const int t = threadIdx.x;
    const int w = t >> 6, lane = t & 63;
    const int l16 = lane & 15, quad = lane >> 4;
    const int m0 = blockIdx.y * 64;
    const int r0 = (w >> 1) * 32;
    const int c0 = (w & 1) * 64;

    floatx4 acc[2][4] = {};

    const int arow = t >> 2;
    const int skp = (t & 3) * 8;
    const int wbaseA = (t & ~63) * 8;

    for (int k0 = 0; k0 < K; k0 += 32) {
        int gr = m0 + arow; if (gr >= M) gr = M - 1;
        const ushort_t* gpa = A + (size_t)gr * K + k0 + skp;
        __builtin_amdgcn_global_load_lds((const __attribute__((address_space(1))) void*)gpa,
            (__attribute__((address_space(3))) void*)(As + wbaseA), 16, 0, 0);
        #pragma unroll
        for (int j = 0; j < 2; ++j) {
            int r = (j * 256 + t) >> 2;
            const ushort_t* gpb = Bt + (size_t)r * K + k0 + skp;
            __builtin_amdgcn_global_load_lds((const __attribute__((address_space(1))) void*)gpb,
                (__attribute__((address_space(3))) void*)(Bs + (j * 256 + (t & ~63)) * 8), 16, 0, 0);
        }
        __syncthreads();

        short8 af[2], bf[4];
        #pragma unroll
        for (int i = 0; i < 2; ++i)
            af[i] = *(const short8*)(As + (r0 + i * 16 + l16) * 32 + quad * 8);
        #pragma unroll
        for (int j = 0; j < 4; ++j)
            bf[j] = *(const short8*)(Bs + (c0 + j * 16 + l16) * 32 + quad * 8);
        #pragma unroll
        for (int i = 0; i < 2; ++i)
            #pragma unroll
            for (int j = 0; j < 4; ++j)
                acc[i][j] = __builtin_amdgcn_mfma_f32_16x16x32_bf16(af[i], bf[j], acc[i][j], 0, 0, 0);
        __syncthreads();
    }

    float alv[4], arv[4];
    #pragma unroll
    for (int j = 0; j < 4; ++j) {
        int col = c0 + j * 16 + l16;
        alv[j] = al[col];
        arv[j] = ar[col];
    }
    #pragma unroll
    for (int i = 0; i < 2; ++i) {
        #pragma unroll
        for (int r = 0; r < 4; ++r) {
            int lrow = r0 + i * 16 + quad * 4 + r;
            int row = m0 + lrow;
            if (row < M) {
                #pragma unroll
                for (int j = 0; j < 4; ++j)
                    C[(size_t)row * N + c0 + j * 16 + l16] = f2bf(acc[i][j][r]);
            }
            float p = acc[i][0][r] * alv[0] + acc[i][1][r] * alv[1]
                    + acc[i][2][r] * alv[2] + acc[i][3][r] * alv[3];
            float q = acc[i][0][r] * arv[0] + acc[i][1][r] * arv[1]
                    + acc[i][2][r] * arv[2] + acc[i][3][r] * arv[3];
            #pragma unroll
            for (int o = 8; o > 0; o >>= 1) {
                p += __shfl_down(p, o);
                q += __shfl_down(q, o);
            }
            if (l16 == 0) {
                elp[lrow][w & 1] = p;
                erp[lrow][w & 1] = q;
            }
        }
    }
    __syncthreads();
    if (t < 64) {
        int row = m0 + t;
        if (row < M) {
            el[row] = elp[t][0] + elp[t][1];
            er[row] = erp[t][0] + erp[t][1];
        }
    }
}

// ---------------- layer 1 aggregate: inline weights (LDS chunks) + 4-way unroll ----------------
// block = 256 threads = 1 node; agg thread t covers elems 2t,2t+1 (head h = t>>5).
// Weight phase: thread t -> edge (t>>3), head (t&7): one exp per (edge,head).
__global__ __launch_bounds__(256) void k_agg1(const uint_t* __restrict__ fb,
                                              const float* __restrict__ el, const float* __restrict__ er,
                                              const float* __restrict__ b1,
                                              const int* __restrict__ indptr, const int* __restrict__ csr_src,
                                              uint_t* __restrict__ h1b, int n) {
    __shared__ float wch[32 * 8];
    __shared__ int sch[32];
    int node = blockIdx.x;
    int t = threadIdx.x;
    int h = t >> 5;
    int et = t >> 3, hw = t & 7;
    int e0 = indptr[node], e1 = indptr[node + 1];
    int deg = e1 - e0;
    float erv = er[node * NHEAD + hw];
    float a0 = 0.f, a1 = 0.f, den = 0.f;

    for (int base = 0; base < deg; base += 32) {
        int cnt = min(32, deg - base);
        if (et < cnt) {
            int s = csr_src[e0 + base + et];
            if (hw == 0) sch[et] = s;
            float x = el[s * NHEAD + hw] + erv;
            x = (x > 0.f) ? x : 0.2f * x;
            wch[et * 8 + hw] = __expf(x);
        }
        __syncthreads();
        int e = 0;
        for (; e + 3 < cnt; e += 4) {
            int s0 = sch[e], s1 = sch[e + 1], s2 = sch[e + 2], s3 = sch[e + 3];
            float w0 = wch[e * 8 + h], w1 = wch[(e + 1) * 8 + h];
            float w2 = wch[(e + 2) * 8 + h], w3 = wch[(e + 3) * 8 + h];
            uint_t u0 = fb[(size_t)s0 * 256 + t];
            uint_t u1 = fb[(size_t)s1 * 256 + t];
            uint_t u2 = fb[(size_t)s2 * 256 + t];
            uint_t u3 = fb[(size_t)s3 * 256 + t];
            den += (w0 + w1) + (w2 + w3);
            a0 += w0 * bf2f(u0 & 0xFFFF) + w1 * bf2f(u1 & 0xFFFF)
                + w2 * bf2f(u2 & 0xFFFF) + w3 * bf2f(u3 & 0xFFFF);
            a1 += w0 * bf2f(u0 >> 16) + w1 * bf2f(u1 >> 16)
                + w2 * bf2f(u2 >> 16) + w3 * bf2f(u3 >> 16);
        }
        for (; e < cnt; ++e) {
            int s = sch[e];
            float ww = wch[e * 8 + h];
            uint_t u = fb[(size_t)s * 256 + t];
            den += ww;
            a0 += ww * bf2f(u & 0xFFFF);
            a1 += ww * bf2f(u >> 16);
        }
        __syncthreads();
    }

    float inv = 1.f / den;
    float v0 = a0 * inv + b1[2 * t];
    float v1 = a1 * inv + b1[2 * t + 1];
    v0 = (v0 > 0.f) ? v0 : (__expf(v0) - 1.f);
    v1 = (v1 > 0.f) ? v1 : (__expf(v1) - 1.f);
    h1b[(size_t)node * 256 + t] = (uint_t)f2bf(v0) | ((uint_t)f2bf(v1) << 16);
}

// ---------------- layer 2 aggregate: inline weights (per-wave LDS) + 4-way unroll ----------------
__global__ __launch_bounds__(256) void k_agg2(const uint_t* __restrict__ fb2,
                                              const float* __restrict__ el2, const float* __restrict__ er2,
                                              const float* __restrict__ b2,
                                              const int* __restrict__ indptr, const int* __restrict__ csr_src,
                                              float* __restrict__ out, int n) {
    __shared__ float wch[4][64];
    __shared__ int sch[4][64];
    int w = threadIdx.x >> 6;
    int wid = blockIdx.x * 4 + w;
    int lane = threadIdx.x & 63;
    if (wid >= n) return;                       // wave-uniform
    float erv = er2[wid];
    int e0 = indptr[wid], e1 = indptr[wid + 1];
    int deg = e1 - e0;
    float a0 = 0.f, a1 = 0.f, den = 0.f;

    for (int base = 0; base < deg; base += 64) {
        int cnt = min(64, deg - base);
        if (lane < cnt) {
            int s = csr_src[e0 + base + lane];
            sch[w][lane] = s;
            float x = el2[s] + erv;
            x = (x > 0.f) ? x : 0.2f * x;
            wch[w][lane] = __expf(x);
        }
        __builtin_amdgcn_wave_barrier();        // same-wave LDS RAW: order only, no cost
        int e = 0;
        for (; e + 3 < cnt; e += 4) {
            int s0 = sch[w][e], s1 = sch[w][e + 1], s2 = sch[w][e + 2], s3 = sch[w][e + 3];
            float w0 = wch[w][e], w1 = wch[w][e + 1], w2 = wch[w][e + 2], w3 = wch[w][e + 3];
            uint_t u0 = fb2[(size_t)s0 * 64 + lane];
            uint_t u1 = fb2[(size_t)s1 * 64 + lane];
            uint_t u2 = fb2[(size_t)s2 * 64 + lane];
            uint_t u3 = fb2[(size_t)s3 * 64 + lane];
            den += (w0 + w1) + (w2 + w3);
            a0 += w0 * bf2f(u0 & 0xFFFF) + w1 * bf2f(u1 & 0xFFFF)
                + w2 * bf2f(u2 & 0xFFFF) + w3 * bf2f(u3 & 0xFFFF);
            a1 += w0 * bf2f(u0 >> 16) + w1 * bf2f(u1 >> 16)
                + w2 * bf2f(u2 >> 16) + w3 * bf2f(u3 >> 16);
        }
        for (; e < cnt; ++e) {
            int s = sch[w][e];
            float ww = wch[w][e];
            uint_t u = fb2[(size_t)s * 64 + lane];
            den += ww;
            a0 += ww * bf2f(u & 0xFFFF);
            a1 += ww * bf2f(u >> 16);
        }
        __builtin_amdgcn_wave_barrier();
    }

    float inv = 1.f / den;
    float2 o;
    o.x = a0 * inv + b2[2 * lane];
    o.y = a1 * inv + b2[2 * lane + 1];
    ((float2*)out)[(size_t)wid * 64 + lane] = o;
}

extern "C" void kernel_launch(void* const* d_in, const int* in_sizes, int n_in,
                              void* d_out, int out_size, void* d_ws, size_t ws_size,
                              hipStream_t stream) {
    const float* x   = (const float*)d_in[0];
    const int*   ei  = (const int*)d_in[1];
    const float* W1  = (const float*)d_in[2];
    const float* al1 = (const float*)d_in[3];
    const float* ar1 = (const float*)d_in[4];
    const float* b1  = (const float*)d_in[5];
    const float* W2  = (const float*)d_in[6];
    const float* al2 = (const float*)d_in[7];
    const float* ar2 = (const float*)d_in[8];
    const float* b2  = (const float*)d_in[9];

    const int n  = in_sizes[0] / NFEAT;   // 50000
    const int E  = in_sizes[1] / 2;       // 400000
    const int ET = E + n;
    const int* srcA = ei;
    const int* dstA = ei + E;

    char* ws = (char*)d_ws;
    size_t off = 0;
    auto alloc = [&](size_t bytes) -> void* {
        void* p = ws + off;
        off += (bytes + 255) & ~(size_t)255;
        return p;
    };
    ushort_t* xb     = (ushort_t*)alloc((size_t)n * NFEAT * 2);
    ushort_t* feat1b = (ushort_t*)alloc((size_t)n * HID1 * 2);
    ushort_t* h1b    = (ushort_t*)alloc((size_t)n * HID1 * 2);
    ushort_t* feat2b = (ushort_t*)alloc((size_t)n * NOUT * 2);
    ushort_t* W1t    = (ushort_t*)alloc((size_t)NFEAT * HID1 * 2);
    ushort_t* W2t    = (ushort_t*)alloc((size_t)HID1 * NOUT * 2);
    float* el1 = (float*)alloc((size_t)n * NHEAD * 4);
    float* er1 = (float*)alloc((size_t)n * NHEAD * 4);
    float* el2 = (float*)alloc((size_t)n * 4);
    float* er2 = (float*)alloc((size_t)n * 4);
    int* indptr = (int*)alloc((size_t)(n + 1) * 4);
    int* deg    = (int*)alloc((size_t)2 * n * 4);   // deg[n] then cnt[n], contiguous
    int* cnt    = deg + n;
    int* csr    = (int*)alloc((size_t)ET * 4);

    hipMemsetAsync(deg, 0, (size_t)2 * n * 4, stream);

    // fused prep (cast + W transposes + hist)
    const int c0 = (n * NFEAT / 4) / 256;
    const int c1 = c0 + (NFEAT * HID1) / 256;
    const int c2 = c1 + (HID1 * NOUT) / 256;
    const int c3 = c2 + (ET + 255) / 256;
    k_prep<<<c3, 256, 0, stream>>>(x, xb, W1, W1t, W2, W2t, dstA, deg, n, E, c0, c1, c2);

    k_scan<<<1, 1024, 0, stream>>>(deg, indptr, n);
    k_fill<<<(ET + 255) / 256, 256, 0, stream>>>(srcA, dstA, E, n, indptr, cnt, csr);

    // layer 1
    k_gemm1<<<dim3(HID1 / 256, (n + 127) / 128), 256, 0, stream>>>(xb, W1t, feat1b, al1, ar1, el1, er1, n);
    k_agg1<<<n, 256, 0, stream>>>((const uint_t*)feat1b, el1, er1, b1, indptr, csr, (uint_t*)h1b, n);

    // layer 2
    k_gemm2<<<dim3(1, (n + 63) / 64), 256, 0, stream>>>(h1b, W2t, feat2b, al2, ar2, el2, er2, n);
    k_agg2<<<(n + 3) / 4, 256, 0, stream>>>((const uint_t*)feat2b, el2, er2, b2, indptr, csr, (float*)d_out, n);
}

// Round 8
// 384.166 us; speedup vs baseline: 1.0075x; 1.0075x over previous
//
#include <hip/hip_runtime.h>

#define NFEAT 256
#define NHID 64
#define NHEAD 8
#define HID1 512   // NHEAD*NHID
#define NOUT 128

typedef unsigned short ushort_t;
typedef unsigned int uint_t;
typedef __attribute__((ext_vector_type(8))) short short8;
typedef __attribute__((ext_vector_type(4))) float floatx4;
typedef __attribute__((ext_vector_type(4))) ushort_t ushort4_t;

static __device__ __forceinline__ float bf2f(uint_t s) {
    return __uint_as_float(s << 16);
}
static __device__ __forceinline__ ushort_t f2bf(float f) {
    uint_t u = __float_as_uint(f);
    u += 0x7FFF + ((u >> 16) & 1);   // RNE; inputs finite
    return (ushort_t)(u >> 16);
}

// ---------------- fused prep: cast x, transpose W1/W2, degree histogram ----------------
__global__ void k_prep(const float* __restrict__ x, ushort_t* __restrict__ xb,
                       const float* __restrict__ W1, ushort_t* __restrict__ W1t,
                       const float* __restrict__ W2, ushort_t* __restrict__ W2t,
                       const int* __restrict__ dstA, int* __restrict__ deg,
                       int n, int E, int c0, int c1, int c2) {
    int blk = blockIdx.x;
    int t = threadIdx.x;
    if (blk < c0) {                       // cast x -> bf16, 4 elems/thread
        int i = blk * 256 + t;
        floatx4 f = ((const floatx4*)x)[i];
        ushort4_t o;
        #pragma unroll
        for (int j = 0; j < 4; ++j) o[j] = f2bf(f[j]);
        ((ushort4_t*)xb)[i] = o;
    } else if (blk < c1) {                // W1[K][N] -> W1t[N][K] bf16
        int i = (blk - c0) * 256 + t;
        int nn = i / NFEAT, kk = i % NFEAT;
        W1t[i] = f2bf(W1[(size_t)kk * HID1 + nn]);
    } else if (blk < c2) {                // W2[K][N] -> W2t[N][K] bf16
        int i = (blk - c1) * 256 + t;
        int nn = i / HID1, kk = i % HID1;
        W2t[i] = f2bf(W2[(size_t)kk * NOUT + nn]);
    } else {                              // degree histogram (self-loops appended)
        int i = (blk - c2) * 256 + t;
        if (i < E + n) {
            int d = (i < E) ? dstA[i] : (i - E);
            atomicAdd(&deg[d], 1);
        }
    }
}

// ---------------- single-block scan ----------------
__global__ __launch_bounds__(1024) void k_scan(const int* __restrict__ deg, int* __restrict__ indptr, int n) {
    __shared__ int part[1024];
    int t = threadIdx.x;
    int chunk = (n + 1023) >> 10;
    int b = t * chunk;
    int e = min(b + chunk, n);
    int s = 0;
    int i = b;
    for (; i + 3 < e; i += 4)
        s += (deg[i] + deg[i + 1]) + (deg[i + 2] + deg[i + 3]);
    for (; i < e; ++i) s += deg[i];
    part[t] = s;
    __syncthreads();
    for (int off = 1; off < 1024; off <<= 1) {
        int v = (t >= off) ? part[t - off] : 0;
        __syncthreads();
        part[t] += v;
        __syncthreads();
    }
    int run = (t == 0) ? 0 : part[t - 1];
    i = b;
    for (; i + 3 < e; i += 4) {
        int d0 = deg[i], d1 = deg[i + 1], d2 = deg[i + 2], d3 = deg[i + 3];
        indptr[i] = run; run += d0;
        indptr[i + 1] = run; run += d1;
        indptr[i + 2] = run; run += d2;
        indptr[i + 3] = run; run += d3;
    }
    for (; i < e; ++i) { indptr[i] = run; run += deg[i]; }
    if (t == 1023) indptr[n] = part[1023];
}

// ---------------- fill + layer-1 edge weights (runs AFTER gemm1) ----------------
// One thread per edge: place in CSR, compute all 8 head softmax weights.
__global__ void k_fillw(const int* __restrict__ srcA, const int* __restrict__ dstA, int E, int n,
                        const int* __restrict__ indptr, int* __restrict__ cnt,
                        int* __restrict__ csr_src,
                        const float* __restrict__ el, const float* __restrict__ er,
                        float* __restrict__ wcsr) {
    int i = blockIdx.x * blockDim.x + threadIdx.x;
    if (i >= E + n) return;
    int s, d;
    if (i < E) { s = srcA[i]; d = dstA[i]; } else { s = i - E; d = s; }
    int pos = indptr[d] + atomicAdd(&cnt[d], 1);
    csr_src[pos] = s;
    floatx4 el0 = *(const floatx4*)(el + (size_t)s * NHEAD);
    floatx4 el1v = *(const floatx4*)(el + (size_t)s * NHEAD + 4);
    floatx4 er0 = *(const floatx4*)(er + (size_t)d * NHEAD);
    floatx4 er1v = *(const floatx4*)(er + (size_t)d * NHEAD + 4);
    floatx4 w0, w1;
    #pragma unroll
    for (int h = 0; h < 4; ++h) {
        float xa = el0[h] + er0[h];
        xa = (xa > 0.f) ? xa : 0.2f * xa;
        w0[h] = __expf(xa);
        float xb2 = el1v[h] + er1v[h];
        xb2 = (xb2 > 0.f) ? xb2 : 0.2f * xb2;
        w1[h] = __expf(xb2);
    }
    *(floatx4*)(wcsr + (size_t)pos * NHEAD) = w0;
    *(floatx4*)(wcsr + (size_t)pos * NHEAD + 4) = w1;
}

// ---------------- GEMM1: 128x256 tile + fused el1/er1 epilogue ----------------
__global__ __launch_bounds__(256) void k_gemm1(const ushort_t* __restrict__ A,
                                               const ushort_t* __restrict__ Bt,
                                               ushort_t* __restrict__ C,
                                               const float* __restrict__ al,
                                               const float* __restrict__ ar,
                                               float* __restrict__ el, float* __restrict__ er,
                                               int M) {
    const int N = HID1, K = NFEAT;
    __shared__ __align__(16) ushort_t As[128 * 32];   // 8 KB
    __shared__ __align__(16) ushort_t Bs[256 * 32];   // 16 KB
    const int t = threadIdx.x;
    const int w = t >> 6, lane = t & 63;
    const int l16 = lane & 15, quad = lane >> 4;
    const int m0 = blockIdx.y * 128, n0 = blockIdx.x * 256;
    const int r0 = (w >> 1) * 64;
    const int c0 = (w & 1) * 128;     // 2 heads per wave

    floatx4 acc[4][8] = {};

    const int skp = (t & 3) * 8;
    for (int k0 = 0; k0 < K; k0 += 32) {
        #pragma unroll
        for (int j = 0; j < 2; ++j) {
            int r = (j * 256 + t) >> 2;
            int gr = m0 + r; if (gr >= M) gr = M - 1;
            const ushort_t* gp = A + (size_t)gr * K + k0 + skp;
            __builtin_amdgcn_global_load_lds((const __attribute__((address_space(1))) void*)gp,
                (__attribute__((address_space(3))) void*)(As + (j * 256 + (t & ~63)) * 8), 16, 0, 0);
        }
        #pragma unroll
        for (int j = 0; j < 4; ++j) {
            int r = (j * 256 + t) >> 2;
            const ushort_t* gp = Bt + (size_t)(n0 + r) * K + k0 + skp;
            __builtin_amdgcn_global_load_lds((const __attribute__((address_space(1))) void*)gp,
                (__attribute__((address_space(3))) void*)(Bs + (j * 256 + (t & ~63)) * 8), 16, 0, 0);
        }
        __syncthreads();

        short8 af[4], bf[8];
        #pragma unroll
        for (int i = 0; i < 4; ++i)
            af[i] = *(const short8*)(As + (r0 + i * 16 + l16) * 32 + quad * 8);
        #pragma unroll
        for (int j = 0; j < 8; ++j)
            bf[j] = *(const short8*)(Bs + (c0 + j * 16 + l16) * 32 + quad * 8);
        #pragma unroll
        for (int i = 0; i < 4; ++i)
            #pragma unroll
            for (int j = 0; j < 8; ++j)
                acc[i][j] = __builtin_amdgcn_mfma_f32_16x16x32_bf16(af[i], bf[j], acc[i][j], 0, 0, 0);
        __syncthreads();
    }

    // C store
    #pragma unroll
    for (int i = 0; i < 4; ++i) {
        #pragma unroll
        for (int r = 0; r < 4; ++r) {
            int row = m0 + r0 + i * 16 + quad * 4 + r;
            if (row < M) {
                #pragma unroll
                for (int j = 0; j < 8; ++j)
                    C[(size_t)row * N + n0 + c0 + j * 16 + l16] = f2bf(acc[i][j][r]);
            }
        }
    }

    // fused el/er
    float alv[8], arv[8];
    #pragma unroll
    for (int j = 0; j < 8; ++j) {
        int col = n0 + c0 + j * 16 + l16;
        alv[j] = al[col];
        arv[j] = ar[col];
    }
    int head0 = (n0 + c0) >> 6;
    #pragma unroll
    for (int i = 0; i < 4; ++i) {
        #pragma unroll
        for (int r = 0; r < 4; ++r) {
            float pa = acc[i][0][r] * alv[0] + acc[i][1][r] * alv[1]
                     + acc[i][2][r] * alv[2] + acc[i][3][r] * alv[3];
            float qa = acc[i][0][r] * arv[0] + acc[i][1][r] * arv[1]
                     + acc[i][2][r] * arv[2] + acc[i][3][r] * arv[3];
            float pb = acc[i][4][r] * alv[4] + acc[i][5][r] * alv[5]
                     + acc[i][6][r] * alv[6] + acc[i][7][r] * alv[7];
            float qb = acc[i][4][r] * arv[4] + acc[i][5][r] * arv[5]
                     + acc[i][6][r] * arv[6] + acc[i][7][r] * arv[7];
            #pragma unroll
            for (int o = 8; o > 0; o >>= 1) {
                pa += __shfl_down(pa, o);
                qa += __shfl_down(qa, o);
                pb += __shfl_down(pb, o);
                qb += __shfl_down(qb, o);
            }
            if (l16 == 0) {
                int row = m0 + r0 + i * 16 + quad * 4 + r;
                if (row < M) {
                    el[row * NHEAD + head0] = pa;
                    er[row * NHEAD + head0] = qa;
                    el[row * NHEAD + head0 + 1] = pb;
                    er[row * NHEAD + head0 + 1] = qb;
                }
            }
        }
    }
}

// ---------------- GEMM2: 64x128 tile + fused el2/er2 epilogue ----------------
__global__ __launch_bounds__(256) void k_gemm2(const ushort_t* __restrict__ A,
                                               const ushort_t* __restrict__ Bt,
                                               ushort_t* __restrict__ C,
                                               const float* __restrict__ al,
                                               const float* __restrict__ ar,
                                               float* __restrict__ el, float* __restrict__ er,
                                               int M) {
    const int N = NOUT, K = HID1;
    __shared__ __align__(16) ushort_t As[64 * 32];
    __shared__ __align__(16) ushort_t Bs[128 * 32];
    __shared__ float elp[64][2], erp[64][2];
    const int t = threadIdx.x;
    const int w = t >> 6, lane = t & 63;
    const int l16 = lane & 15, quad = lane >> 4;
    const int m0 = blockIdx.y * 64;
    const int r0 = (w >> 1) * 32;
    const int c0 = (w & 1) * 64;

    floatx4 acc[2][4] = {};

    const int arow = t >> 2;
    const int skp = (t & 3) * 8;
    const int wbaseA = (t & ~63) * 8;

    for (int k0 = 0; k0 < K; k0 += 32) {
        int gr = m0 + arow; if (gr >= M) gr = M - 1;
        const ushort_t* gpa = A + (size_t)gr * K + k0 + skp;
        __builtin_amdgcn_global_load_lds((const __attribute__((address_space(1))) void*)gpa,
            (__attribute__((address_space(3))) void*)(As + wbaseA), 16, 0, 0);
        #pragma unroll
        for (int j = 0; j < 2; ++j) {
            int r = (j * 256 + t) >> 2;
            const ushort_t* gpb = Bt + (size_t)r * K + k0 + skp;
            __builtin_amdgcn_global_load_lds((const __attribute__((address_space(1))) void*)gpb,
                (__attribute__((address_space(3))) void*)(Bs + (j * 256 + (t & ~63)) * 8), 16, 0, 0);
        }
        __syncthreads();

        short8 af[2], bf[4];
        #pragma unroll
        for (int i = 0; i < 2; ++i)
            af[i] = *(const short8*)(As + (r0 + i * 16 + l16) * 32 + quad * 8);
        #pragma unroll
        for (int j = 0; j < 4; ++j)
            bf[j] = *(const short8*)(Bs + (c0 + j * 16 + l16) * 32 + quad * 8);
        #pragma unroll
        for (int i = 0; i < 2; ++i)
            #pragma unroll
            for (int j = 0; j < 4; ++j)
                acc[i][j] = __builtin_amdgcn_mfma_f32_16x16x32_bf16(af[i], bf[j], acc[i][j], 0, 0, 0);
        __syncthreads();
    }

    float alv[4], arv[4];
    #pragma unroll
    for (int j = 0; j < 4; ++j) {
        int col = c0 + j * 16 + l16;
        alv[j] = al[col];
        arv[j] = ar[col];
    }
    #pragma unroll
    for (int i = 0; i < 2; ++i) {
        #pragma unroll
        for (int r = 0; r < 4; ++r) {
            int lrow = r0 + i * 16 + quad * 4 + r;
            int row = m0 + lrow;
            if (row < M) {
                #pragma unroll
                for (int j = 0; j < 4; ++j)
                    C[(size_t)row * N + c0 + j * 16 + l16] = f2bf(acc[i][j][r]);
            }
            float p = acc[i][0][r] * alv[0] + acc[i][1][r] * alv[1]
                    + acc[i][2][r] * alv[2] + acc[i][3][r] * alv[3];
            float q = acc[i][0][r] * arv[0] + acc[i][1][r] * arv[1]
                    + acc[i][2][r] * arv[2] + acc[i][3][r] * arv[3];
            #pragma unroll
            for (int o = 8; o > 0; o >>= 1) {
                p += __shfl_down(p, o);
                q += __shfl_down(q, o);
            }
            if (l16 == 0) {
                elp[lrow][w & 1] = p;
                erp[lrow][w & 1] = q;
            }
        }
    }
    __syncthreads();
    if (t < 64) {
        int row = m0 + t;
        if (row < M) {
            el[row] = elp[t][0] + elp[t][1];
            er[row] = erp[t][0] + erp[t][1];
        }
    }
}

// ---------------- layer 1 aggregate: precomputed weights, 4-way unroll ----------------
__global__ __launch_bounds__(256) void k_agg1(const uint_t* __restrict__ fb, const float* __restrict__ wcsr,
                                              const float* __restrict__ b1,
                                              const int* __restrict__ indptr, const int* __restrict__ csr_src,
                                              uint_t* __restrict__ h1b, int n) {
    int node = blockIdx.x;
    int t = threadIdx.x;
    int h = t >> 5;
    int e0 = indptr[node], e1 = indptr[node + 1];
    float a0 = 0.f, a1 = 0.f, den = 0.f;
    int e = e0;
    for (; e + 3 < e1; e += 4) {
        int s0 = csr_src[e], s1 = csr_src[e + 1], s2 = csr_src[e + 2], s3 = csr_src[e + 3];
        float w0 = wcsr[(size_t)e * NHEAD + h];
        float w1 = wcsr[(size_t)(e + 1) * NHEAD + h];
        float w2 = wcsr[(size_t)(e + 2) * NHEAD + h];
        float w3 = wcsr[(size_t)(e + 3) * NHEAD + h];
        uint_t u0 = fb[(size_t)s0 * 256 + t];
        uint_t u1 = fb[(size_t)s1 * 256 + t];
        uint_t u2 = fb[(size_t)s2 * 256 + t];
        uint_t u3 = fb[(size_t)s3 * 256 + t];
        den += (w0 + w1) + (w2 + w3);
        a0 += w0 * bf2f(u0 & 0xFFFF) + w1 * bf2f(u1 & 0xFFFF)
            + w2 * bf2f(u2 & 0xFFFF) + w3 * bf2f(u3 & 0xFFFF);
        a1 += w0 * bf2f(u0 >> 16) + w1 * bf2f(u1 >> 16)
            + w2 * bf2f(u2 >> 16) + w3 * bf2f(u3 >> 16);
    }
    for (; e < e1; ++e) {
        int s = csr_src[e];
        float w = wcsr[(size_t)e * NHEAD + h];
        uint_t u = fb[(size_t)s * 256 + t];
        den += w;
        a0 += w * bf2f(u & 0xFFFF);
        a1 += w * bf2f(u >> 16);
    }
    float inv = 1.f / den;
    float v0 = a0 * inv + b1[2 * t];
    float v1 = a1 * inv + b1[2 * t + 1];
    v0 = (v0 > 0.f) ? v0 : (__expf(v0) - 1.f);
    v1 = (v1 > 0.f) ? v1 : (__expf(v1) - 1.f);
    h1b[(size_t)node * 256 + t] = (uint_t)f2bf(v0) | ((uint_t)f2bf(v1) << 16);
}

// ---------------- layer 2 aggregate: inline weights (per-wave LDS) + 4-way unroll ----------------
__global__ __launch_bounds__(256) void k_agg2(const uint_t* __restrict__ fb2,
                                              const float* __restrict__ el2, const float* __restrict__ er2,
                                              const float* __restrict__ b2,
                                              const int* __restrict__ indptr, const int* __restrict__ csr_src,
                                              float* __restrict__ out, int n) {
    __shared__ float wch[4][64];
    __shared__ int sch[4][64];
    int w = threadIdx.x >> 6;
    int wid = blockIdx.x * 4 + w;
    int lane = threadIdx.x & 63;
    if (wid >= n) return;                       // wave-uniform
    float erv = er2[wid];
    int e0 = indptr[wid], e1 = indptr[wid + 1];
    int deg = e1 - e0;
    float a0 = 0.f, a1 = 0.f, den = 0.f;

    for (int base = 0; base < deg; base += 64) {
        int cnt = min(64, deg - base);
        if (lane < cnt) {
            int s = csr_src[e0 + base + lane];
            sch[w][lane] = s;
            float x = el2[s] + erv;
            x = (x > 0.f) ? x : 0.2f * x;
            wch[w][lane] = __expf(x);
        }
        __builtin_amdgcn_wave_barrier();
        int e = 0;
        for (; e + 3 < cnt; e += 4) {
            int s0 = sch[w][e], s1 = sch[w][e + 1], s2 = sch[w][e + 2], s3 = sch[w][e + 3];
            float w0 = wch[w][e], w1 = wch[w][e + 1], w2 = wch[w][e + 2], w3 = wch[w][e + 3];
            uint_t u0 = fb2[(size_t)s0 * 64 + lane];
            uint_t u1 = fb2[(size_t)s1 * 64 + lane];
            uint_t u2 = fb2[(size_t)s2 * 64 + lane];
            uint_t u3 = fb2[(size_t)s3 * 64 + lane];
            den += (w0 + w1) + (w2 + w3);
            a0 += w0 * bf2f(u0 & 0xFFFF) + w1 * bf2f(u1 & 0xFFFF)
                + w2 * bf2f(u2 & 0xFFFF) + w3 * bf2f(u3 & 0xFFFF);
            a1 += w0 * bf2f(u0 >> 16) + w1 * bf2f(u1 >> 16)
                + w2 * bf2f(u2 >> 16) + w3 * bf2f(u3 >> 16);
        }
        for (; e < cnt; ++e) {
            int s = sch[w][e];
            float ww = wch[w][e];
            uint_t u = fb2[(size_t)s * 64 + lane];
            den += ww;
            a0 += ww * bf2f(u & 0xFFFF);
            a1 += ww * bf2f(u >> 16);
        }
        __builtin_amdgcn_wave_barrier();
    }

    float inv = 1.f / den;
    float2 o;
    o.x = a0 * inv + b2[2 * lane];
    o.y = a1 * inv + b2[2 * lane + 1];
    ((float2*)out)[(size_t)wid * 64 + lane] = o;
}

extern "C" void kernel_launch(void* const* d_in, const int* in_sizes, int n_in,
                              void* d_out, int out_size, void* d_ws, size_t ws_size,
                              hipStream_t stream) {
    const float* x   = (const float*)d_in[0];
    const int*   ei  = (const int*)d_in[1];
    const float* W1  = (const float*)d_in[2];
    const float* al1 = (const float*)d_in[3];
    const float* ar1 = (const float*)d_in[4];
    const float* b1  = (const float*)d_in[5];
    const float* W2  = (const float*)d_in[6];
    const float* al2 = (const float*)d_in[7];
    const float* ar2 = (const float*)d_in[8];
    const float* b2  = (const float*)d_in[9];

    const int n  = in_sizes[0] / NFEAT;   // 50000
    const int E  = in_sizes[1] / 2;       // 400000
    const int ET = E + n;
    const int* srcA = ei;
    const int* dstA = ei + E;

    char* ws = (char*)d_ws;
    size_t off = 0;
    auto alloc = [&](size_t bytes) -> void* {
        void* p = ws + off;
        off += (bytes + 255) & ~(size_t)255;
        return p;
    };
    ushort_t* xb     = (ushort_t*)alloc((size_t)n * NFEAT * 2);
    ushort_t* feat1b = (ushort_t*)alloc((size_t)n * HID1 * 2);
    ushort_t* h1b    = (ushort_t*)alloc((size_t)n * HID1 * 2);
    ushort_t* feat2b = (ushort_t*)alloc((size_t)n * NOUT * 2);
    ushort_t* W1t    = (ushort_t*)alloc((size_t)NFEAT * HID1 * 2);
    ushort_t* W2t    = (ushort_t*)alloc((size_t)HID1 * NOUT * 2);
    float* el1 = (float*)alloc((size_t)n * NHEAD * 4);
    float* er1 = (float*)alloc((size_t)n * NHEAD * 4);
    float* el2 = (float*)alloc((size_t)n * 4);
    float* er2 = (float*)alloc((size_t)n * 4);
    float* wcsr1 = (float*)alloc((size_t)ET * NHEAD * 4);   // 14.4 MB
    int* indptr = (int*)alloc((size_t)(n + 1) * 4);
    int* deg    = (int*)alloc((size_t)2 * n * 4);   // deg[n] then cnt[n], contiguous
    int* cnt    = deg + n;
    int* csr    = (int*)alloc((size_t)ET * 4);

    hipMemsetAsync(deg, 0, (size_t)2 * n * 4, stream);

    // fused prep (cast + W transposes + hist)
    const int c0 = (n * NFEAT / 4) / 256;
    const int c1 = c0 + (NFEAT * HID1) / 256;
    const int c2 = c1 + (HID1 * NOUT) / 256;
    const int c3 = c2 + (ET + 255) / 256;
    k_prep<<<c3, 256, 0, stream>>>(x, xb, W1, W1t, W2, W2t, dstA, deg, n, E, c0, c1, c2);

    k_scan<<<1, 1024, 0, stream>>>(deg, indptr, n);

    // layer 1 GEMM (+el/er), then CSR fill fused with edge-weight compute
    k_gemm1<<<dim3(HID1 / 256, (n + 127) / 128), 256, 0, stream>>>(xb, W1t, feat1b, al1, ar1, el1, er1, n);
    k_fillw<<<(ET + 255) / 256, 256, 0, stream>>>(srcA, dstA, E, n, indptr, cnt, csr, el1, er1, wcsr1);
    k_agg1<<<n, 256, 0, stream>>>((const uint_t*)feat1b, wcsr1, b1, indptr, csr, (uint_t*)h1b, n);

    // layer 2
    k_gemm2<<<dim3(1, (n + 63) / 64), 256, 0, stream>>>(h1b, W2t, feat2b, al2, ar2, el2, er2, n);
    k_agg2<<<(n + 3) / 4, 256, 0, stream>>>((const uint_t*)feat2b, el2, er2, b2, indptr, csr, (float*)d_out, n);
}